// Round 6
// baseline (248.827 us; speedup 1.0000x reference)
//
#include <hip/hip_runtime.h>
#include <math.h>

// Problem constants: B=4,S=4096,IN=2048,E=16,D=128,A=128,R=4
#define NTOK   16384
#define INDIM  2048
#define NROWS  20      // 16 Wv rows + 4 mlp_w1 rows
#define CHUNK  256     // K-chunk (floats): 1 KB per row, 8 chunks

// workspace (float) layout
#define WS_PKT  0      // PKt[e2][r][e]  : 16*4*16 = 1024
#define WS_D1K  1024   // [e2][e] 256
#define WS_GQK  1280   // [e2][e] 256
#define WS_BQK  1536   // [e2][e] 256
#define WS_SCAL 1792   // m0,q0,mW[4],q1[4],Q2[16] = 26
#define WS_TOT  1818

#define SIM_SCALE 0.08838834764831845f  // 1/sqrt(128)

// s_waitcnt immediate: lgkmcnt(0), vmcnt/expcnt unconstrained (gfx9 encoding)
#define WAITCNT_LGKM0 0xC07F

// ---------------------------------------------------------------------------
// async 16B global -> LDS (global_load_lds_dwordx4); lane l passes base+16*l.
// ---------------------------------------------------------------------------
__device__ __forceinline__ void async16(const float* g, float* l) {
    __builtin_amdgcn_global_load_lds(
        (const __attribute__((address_space(1))) void*)g,
        (__attribute__((address_space(3))) void*)l, 16, 0, 0);
}

// Stage ALL 20 weight rows for one K-chunk (redundant per wave: every wave
// issues the same 20 DMAs so its OWN vmcnt proves the data it reads is
// present — no __syncthreads needed; identical bytes make the race benign).
__device__ __forceinline__ void stage_w(const float* __restrict__ wv,
                                        const float* __restrict__ w1,
                                        float* dst, int goff, int l4) {
    #pragma unroll
    for (int r = 0; r < 16; ++r)
        async16(wv + (r << 11) + goff + l4, dst + r * CHUNK + l4);
    #pragma unroll
    for (int r = 0; r < 4; ++r)
        async16(w1 + (r << 11) + goff + l4, dst + ((16 + r) * CHUNK) + l4);
}

__device__ __forceinline__ void load_h(float4* hr, const float* hb, int c) {
    const float* p = hb + (c << 8);
    hr[0] = *(const float4*)(p);
    hr[1] = *(const float4*)(p + INDIM);
    hr[2] = *(const float4*)(p + 2 * INDIM);
    hr[3] = *(const float4*)(p + 3 * INDIM);
}

// 20 ds_read_b128 + 320 FMA
__device__ __forceinline__ void compute_chunk(float acc[NROWS][4],
                                              const float* wb,
                                              const float4 h[4]) {
    #pragma unroll
    for (int w = 0; w < NROWS; ++w) {
        float4 wf = *(const float4*)(wb + (w << 8));
        #pragma unroll
        for (int t = 0; t < 4; ++t) {
            acc[w][t] = fmaf(h[t].x, wf.x,
                        fmaf(h[t].y, wf.y,
                        fmaf(h[t].z, wf.z,
                        fmaf(h[t].w, wf.w, acc[w][t]))));
        }
    }
}

// ---------------------------------------------------------------------------
// Precompute kernel: 17 blocks x 256 threads (unchanged, known-good).
// ---------------------------------------------------------------------------
__global__ __launch_bounds__(256) void hr_pre2(
    const float* __restrict__ ee, const float* __restrict__ gam,
    const float* __restrict__ bta, const float* __restrict__ w2,
    const float* __restrict__ b2, const float* __restrict__ wq,
    const float* __restrict__ wk, float* __restrict__ ws)
{
    const int tid  = threadIdx.x;
    const int bx   = blockIdx.x;
    const int lane = tid & 63;
    const int wave = tid >> 6;

    if (bx == 16) {
        __shared__ float sacc[26];
        if (tid < 26) sacc[tid] = 0.f;
        __syncthreads();
        float pa[26];
        #pragma unroll
        for (int j = 0; j < 26; ++j) pa[j] = 0.f;
        for (int i = tid; i < 2048; i += 256) {
            float b = b2[i];
            float4 w4 = *(const float4*)(w2 + i * 4);
            float wr[4] = {w4.x, w4.y, w4.z, w4.w};
            pa[0] += b;
            pa[1] += b * b;
            #pragma unroll
            for (int r = 0; r < 4; ++r) {
                pa[2 + r] += wr[r];
                pa[6 + r] += b * wr[r];
                #pragma unroll
                for (int r2 = 0; r2 < 4; ++r2) pa[10 + r * 4 + r2] += wr[r] * wr[r2];
            }
        }
        #pragma unroll
        for (int j = 0; j < 26; ++j) {
            float v = pa[j];
            v += __shfl_xor(v, 32); v += __shfl_xor(v, 16); v += __shfl_xor(v, 8);
            v += __shfl_xor(v, 4);  v += __shfl_xor(v, 2);  v += __shfl_xor(v, 1);
            if (lane == 0) atomicAdd(&sacc[j], v);
        }
        __syncthreads();
        if (tid < 26) ws[WS_SCAL + tid] = sacc[tid] * (1.f / 2048.f);
        return;
    }

    const int e2 = bx;
    __shared__ float sge[128];
    __shared__ float sK[128];
    __shared__ float sWqK[128];
    __shared__ float sred[8];

    float v8[8];
    float s = 0.f;
    #pragma unroll
    for (int j = 0; j < 8; ++j) { v8[j] = ee[tid + j * 256]; s += v8[j]; }
    s += __shfl_xor(s, 32); s += __shfl_xor(s, 16); s += __shfl_xor(s, 8);
    s += __shfl_xor(s, 4);  s += __shfl_xor(s, 2);  s += __shfl_xor(s, 1);
    if (lane == 0) sred[wave] = s;
    __syncthreads();
    const float mu = (sred[0] + sred[1] + sred[2] + sred[3]) * (1.f / 2048.f);
    float q = 0.f;
    #pragma unroll
    for (int j = 0; j < 8; ++j) { float d = v8[j] - mu; q += d * d; }
    q += __shfl_xor(q, 32); q += __shfl_xor(q, 16); q += __shfl_xor(q, 8);
    q += __shfl_xor(q, 4);  q += __shfl_xor(q, 2);  q += __shfl_xor(q, 1);
    if (lane == 0) sred[4 + wave] = q;
    __syncthreads();
    const float rsq = rsqrtf((sred[4] + sred[5] + sred[6] + sred[7]) * (1.f / 2048.f) + 1e-5f);

    if (tid < 128) {
        int idx = (e2 << 7) + tid;
        sge[tid] = (ee[idx] - mu) * rsq * gam[idx] + bta[idx];
    }
    __syncthreads();

    {
        int a = tid >> 1, half = tid & 1;
        const float* wr = wk + (a << 7) + (half << 6);
        const float* gg = sge + (half << 6);
        float acc = 0.f;
        #pragma unroll 8
        for (int j = 0; j < 64; ++j) acc = fmaf(gg[j], wr[j], acc);
        acc += __shfl_xor(acc, 1);
        if (half == 0) sK[a] = acc;
    }
    __syncthreads();

    {
        int d = tid >> 1, half = tid & 1;
        float acc = 0.f;
        #pragma unroll 8
        for (int j = 0; j < 64; ++j) {
            int a = (half << 6) + j;
            acc = fmaf(wq[(a << 7) + d], sK[a], acc);
        }
        acc += __shfl_xor(acc, 1);
        if (half == 0) sWqK[d] = acc;
    }
    __syncthreads();

    {
        int o = tid >> 2, qd = tid & 3;
        int r = o >> 4, e = o & 15;
        float acc = 0.f;
        #pragma unroll 8
        for (int j = 0; j < 32; ++j) {
            int d  = (qd << 5) + j;
            int ed = (e << 7) + d;
            acc = fmaf(w2[ed * 4 + r] * gam[ed], sWqK[d], acc);
        }
        acc += __shfl_xor(acc, 1);
        acc += __shfl_xor(acc, 2);
        if (qd == 0) ws[WS_PKT + (e2 << 6) + (r << 4) + e] = acc;
    }

    if (tid < 192) {
        int kind = tid >> 6;
        int e    = (tid >> 2) & 15;
        int qd   = tid & 3;
        float acc = 0.f;
        #pragma unroll 8
        for (int j = 0; j < 32; ++j) {
            int d  = (qd << 5) + j;
            int ed = (e << 7) + d;
            float w = sWqK[d];
            float t = (kind == 0) ? b2[ed] * gam[ed]
                    : (kind == 1) ? gam[ed]
                                  : bta[ed];
            acc = fmaf(t, w, acc);
        }
        acc += __shfl_xor(acc, 1);
        acc += __shfl_xor(acc, 2);
        if (qd == 0) ws[WS_D1K + (kind << 8) + (e2 << 4) + e] = acc;
    }
}

// ---------------------------------------------------------------------------
// Main kernel v6: 1024 blocks x 256 thr, 16 tokens/block (4/wave).
// NO __syncthreads in the K-loop. Weights staged redundantly by every wave
// into two DISTINCT __shared__ arrays (wtA/wtB) so the compiler's waitcnt
// pass emits fine-grained vmcnt(N) for the previous phase's DMAs instead of
// the vmcnt(0) drain a __syncthreads would force — prefetch DMAs stay in
// flight ACROSS the raw s_barrier (AITER pattern). lgkmcnt(0) before the
// barrier makes the cross-wave WAR on wtA/wtB airtight (all reads complete
// before any wave can issue the next overwrite). Hidden double-buffered in
// registers (aged one full phase before first use).
// ---------------------------------------------------------------------------
__global__ __launch_bounds__(256) void hr_main(
    const float* __restrict__ hidden, const float* __restrict__ wv,
    const float* __restrict__ wvb, const float* __restrict__ w1,
    const float* __restrict__ b1, const float* __restrict__ tab,
    float* __restrict__ out)
{
    __shared__ float wtA[NROWS * CHUNK];   // 20 KB, chunks 0,2,4,6
    __shared__ float wtB[NROWS * CHUNK];   // 20 KB, chunks 1,3,5,7
    __shared__ float red2[16 * NROWS];     // epilogue result

    const int tid  = threadIdx.x;
    const int wave = tid >> 6;
    const int lane = tid & 63;
    const int l4   = lane << 2;
    const int tok0 = (blockIdx.x << 4) + (wave << 2);
    const float* hb = hidden + (size_t)tok0 * INDIM + l4;

    float acc[NROWS][4];
    #pragma unroll
    for (int w = 0; w < NROWS; ++w) {
        acc[w][0] = 0.f; acc[w][1] = 0.f; acc[w][2] = 0.f; acc[w][3] = 0.f;
    }

    float4 hcur[4], hnxt[4];
    stage_w(wv, w1, wtA, 0, l4);     // chunk 0 (own copy -> own vmcnt proof)
    load_h(hcur, hb, 0);

    for (int cc = 0; cc < 4; ++cc) {
        const int c1 = 2 * cc + 1;
        // even phase: prefetch chunk c1 -> wtB/hnxt, compute chunk c1-1 from wtA
        stage_w(wv, w1, wtB, c1 << 8, l4);
        load_h(hnxt, hb, c1);
        compute_chunk(acc, &wtA[l4], hcur);          // waits vmcnt(24) (aged), not 0
        __builtin_amdgcn_s_waitcnt(WAITCNT_LGKM0);   // my wtA reads are DONE
        __builtin_amdgcn_s_barrier();                // raw: no vmcnt drain
        __builtin_amdgcn_sched_barrier(0);           // keep DMAs below barrier
        // odd phase: prefetch chunk c1+1 -> wtA/hcur, compute chunk c1 from wtB
        if (cc != 3) {
            stage_w(wv, w1, wtA, (c1 + 1) << 8, l4);
            load_h(hcur, hb, c1 + 1);
        }
        compute_chunk(acc, &wtB[l4], hnxt);
        __builtin_amdgcn_s_waitcnt(WAITCNT_LGKM0);
        __builtin_amdgcn_s_barrier();
        __builtin_amdgcn_sched_barrier(0);
    }

    __syncthreads();   // full drain (each wave's own DMAs) before aliasing wtA/wtB

    // ---- reduction: 2 butterfly levels -> 16 partials per (w,t) ----
    #pragma unroll
    for (int w = 0; w < NROWS; ++w) {
        #pragma unroll
        for (int t = 0; t < 4; ++t) {
            float v = acc[w][t];
            v += __shfl_xor(v, 32);
            v += __shfl_xor(v, 16);
            acc[w][t] = v;     // lane l holds partial for i = l&15
        }
    }
    // scatter into dead weight buffers: w<10 -> wtA, w>=10 -> wtB
    {
        const int q = lane >> 4, i = lane & 15;
        #pragma unroll
        for (int w = 0; w < NROWS; ++w) {
            if (q == w / 5) {
                float* buf = (w < 10) ? wtA : wtB;
                const int wi = (w < 10) ? w : (w - 10);
                #pragma unroll
                for (int t = 0; t < 4; ++t)
                    buf[((wave << 2) + t) * 160 + wi * 16 + i] = acc[w][t];
            }
        }
    }
    __syncthreads();

    // gather: 320 (tok,w) pairs, sum 16 partials each -> red2[tok][w]
    #pragma unroll
    for (int pp = 0; pp < 2; ++pp) {
        const int p = tid + (pp << 8);
        if (p < 320) {
            const int w = p >> 4, tok = p & 15;
            const float* buf = (w < 10) ? wtA : wtB;
            const int wi = (w < 10) ? w : (w - 10);
            const float4* rp = (const float4*)&buf[tok * 160 + wi * 16];
            float4 r0 = rp[0], r1 = rp[1], r2 = rp[2], r3 = rp[3];
            float s = (r0.x + r0.y + r0.z + r0.w) + (r1.x + r1.y + r1.z + r1.w)
                    + (r2.x + r2.y + r2.z + r2.w) + (r3.x + r3.y + r3.z + r3.w);
            red2[tok * NROWS + w] = s;
        }
    }
    __syncthreads();

    // ---- tail: 16 threads per token, thread = (tok, e) ----
    const int tok = tid >> 4;
    const int e   = tid & 15;

    float ig[16];
    #pragma unroll
    for (int j = 0; j < 16; ++j) ig[j] = red2[tok * NROWS + j] + wvb[j];
    float h[4];
    #pragma unroll
    for (int r = 0; r < 4; ++r) h[r] = fmaxf(red2[tok * NROWS + 16 + r] + b1[r], 0.f);

    float muT = tab[WS_SCAL + 0];
    float e2m = tab[WS_SCAL + 1];
    #pragma unroll
    for (int r = 0; r < 4; ++r) {
        muT = fmaf(h[r], tab[WS_SCAL + 2 + r], muT);
        e2m = fmaf(2.f * h[r], tab[WS_SCAL + 6 + r], e2m);
        #pragma unroll
        for (int r2 = 0; r2 < 4; ++r2)
            e2m = fmaf(h[r] * h[r2], tab[WS_SCAL + 10 + r * 4 + r2], e2m);
    }
    const float var = e2m - muT * muT;
    const float rsq = rsqrtf(var + 1e-5f);

    float sv[16];
    #pragma unroll
    for (int e2 = 0; e2 < 16; ++e2) {
        float s = tab[WS_D1K + (e2 << 4) + e];
        s = fmaf(h[0], tab[(e2 << 6) + e], s);
        s = fmaf(h[1], tab[(e2 << 6) + 16 + e], s);
        s = fmaf(h[2], tab[(e2 << 6) + 32 + e], s);
        s = fmaf(h[3], tab[(e2 << 6) + 48 + e], s);
        s = fmaf(-muT, tab[WS_GQK + (e2 << 4) + e], s);
        sv[e2] = (rsq * s + tab[WS_BQK + (e2 << 4) + e]) * SIM_SCALE;
    }
    float mx = sv[0];
    #pragma unroll
    for (int e2 = 1; e2 < 16; ++e2) mx = fmaxf(mx, sv[e2]);
    float den = 0.f, gate = 0.f;
    #pragma unroll
    for (int e2 = 0; e2 < 16; ++e2) {
        float p = __expf(sv[e2] - mx);
        den += p;
        gate = fmaf(p, ig[e2], gate);
    }
    gate /= den;

    float gm = gate;
    gm = fmaxf(gm, __shfl_xor(gm, 1));
    gm = fmaxf(gm, __shfl_xor(gm, 2));
    gm = fmaxf(gm, __shfl_xor(gm, 4));
    gm = fmaxf(gm, __shfl_xor(gm, 8));
    float ex = __expf(gate - gm);
    float es = ex;
    es += __shfl_xor(es, 1);
    es += __shfl_xor(es, 2);
    es += __shfl_xor(es, 4);
    es += __shfl_xor(es, 8);
    const float rw = ex / es;

    float v1 = rw; int i1 = e;
    #pragma unroll
    for (int m = 1; m <= 8; m <<= 1) {
        float ov = __shfl_xor(v1, m);
        int   oi = __shfl_xor(i1, m);
        if (ov > v1 || (ov == v1 && oi < i1)) { v1 = ov; i1 = oi; }
    }
    float v2 = (e == i1) ? -INFINITY : rw; int i2 = e;
    #pragma unroll
    for (int m = 1; m <= 8; m <<= 1) {
        float ov = __shfl_xor(v2, m);
        int   oi = __shfl_xor(i2, m);
        if (ov > v2 || (ov == v2 && oi < i2)) { v2 = ov; i2 = oi; }
    }

    float oval = 0.f;
    if (e == i1 || e == i2) {
        float t = __expf((v2 - v1) * 10.f);
        oval = (e == i1) ? (1.f / (1.f + t)) : (t / (1.f + t));
    }
    out[(((size_t)blockIdx.x << 4) + tok) * 16 + e] = oval;
}

// ---------------------------------------------------------------------------
extern "C" void kernel_launch(void* const* d_in, const int* in_sizes, int n_in,
                              void* d_out, int out_size, void* d_ws, size_t ws_size,
                              hipStream_t stream)
{
    const float* hidden = (const float*)d_in[0];   // (4,4096,2048)
    const float* ee     = (const float*)d_in[1];   // (16,128)
    const float* gam    = (const float*)d_in[2];   // (16,128)
    const float* bta    = (const float*)d_in[3];   // (16,128)
    const float* wv     = (const float*)d_in[4];   // (16,2048)
    const float* wvb    = (const float*)d_in[5];   // (16,)
    const float* w1     = (const float*)d_in[6];   // (4,2048)
    const float* b1     = (const float*)d_in[7];   // (4,)
    const float* w2     = (const float*)d_in[8];   // (2048,4)
    const float* b2     = (const float*)d_in[9];   // (2048,)
    const float* wq     = (const float*)d_in[10];  // (128,128)
    const float* wk     = (const float*)d_in[11];  // (128,128)
    float* out = (float*)d_out;
    float* ws  = (float*)d_ws;

    hipLaunchKernelGGL(hr_pre2, dim3(17), dim3(256), 0, stream,
                       ee, gam, bta, w2, b2, wq, wk, ws);
    hipLaunchKernelGGL(hr_main, dim3(NTOK / 16), dim3(256), 0, stream,
                       hidden, wv, wvb, w1, b1, ws, out);
}